// Round 8
// baseline (812.820 us; speedup 1.0000x reference)
//
#include <hip/hip_runtime.h>
#include <hip/hip_bf16.h>
#include <stdint.h>

#define EPSQ 1e-5f

typedef int i32x4 __attribute__((ext_vector_type(4)));

__device__ inline void gload16(const void* g, void* l){
  __builtin_amdgcn_global_load_lds((const __attribute__((address_space(1))) unsigned int*)g,
                                   (__attribute__((address_space(3))) unsigned int*)l, 16, 0, 0);
}

__device__ inline unsigned pack4(float4 v, float s, float lo, float hi){
  int a = (int)fminf(fmaxf(rintf(v.x*s), lo), hi);
  int b = (int)fminf(fmaxf(rintf(v.y*s), lo), hi);
  int c = (int)fminf(fmaxf(rintf(v.z*s), lo), hi);
  int d = (int)fminf(fmaxf(rintf(v.w*s), lo), hi);
  return (unsigned)((a&255)|((b&255)<<8)|((c&255)<<16)|((d&255)<<24));
}

// ---------------- mean|w| two-stage deterministic reduction ----------------
__global__ void absmean_partial(const float* __restrict__ w, int n4, double* __restrict__ partial){
  const float4* w4 = (const float4*)w;
  double s = 0.0;
  int idx = blockIdx.x*blockDim.x + threadIdx.x;
  int stride = gridDim.x*blockDim.x;
  for (int i = idx; i < n4; i += stride){
    float4 v = w4[i];
    s += (double)(fabsf(v.x)+fabsf(v.y)+fabsf(v.z)+fabsf(v.w));
  }
  __shared__ double sm[256];
  sm[threadIdx.x] = s; __syncthreads();
  for (int o=128;o>0;o>>=1){ if (threadIdx.x<o) sm[threadIdx.x]+=sm[threadIdx.x+o]; __syncthreads(); }
  if (threadIdx.x==0) partial[blockIdx.x] = sm[0];
}

__global__ void finalize_scales(const double* __restrict__ partial, float* __restrict__ scalebuf, double inv_n){
  __shared__ double sm[256];
  int t = threadIdx.x;
  double s1 = partial[t] + partial[t+256] + partial[t+512] + partial[t+768];
  sm[t]=s1; __syncthreads();
  for(int o=128;o>0;o>>=1){ if(t<o) sm[t]+=sm[t+o]; __syncthreads(); }
  double m1 = sm[0];
  __syncthreads();
  double s2 = partial[1024+t]+partial[1280+t]+partial[1536+t]+partial[1792+t];
  sm[t]=s2; __syncthreads();
  for(int o=128;o>0;o>>=1){ if(t<o) sm[t]+=sm[t+o]; __syncthreads(); }
  if (t==0){
    scalebuf[0] = 1.0f / fmaxf((float)(m1*inv_n),    EPSQ);   // s_w1
    scalebuf[1] = 1.0f / fmaxf((float)(sm[0]*inv_n), EPSQ);   // s_w2
  }
}

// ---------------- ternary weight quantization -> int8 {-1,0,1} ----------------
__global__ void wquant8(const float* __restrict__ w, char* __restrict__ wq,
                        const float* __restrict__ scalebuf, int which){
  int i = blockIdx.x*256 + threadIdx.x;
  float s = scalebuf[which];
  const float4* w4 = (const float4*)w;
  float4 v0 = w4[(size_t)i*4], v1 = w4[(size_t)i*4+1], v2 = w4[(size_t)i*4+2], v3 = w4[(size_t)i*4+3];
  uint4 pk = make_uint4(pack4(v0,s,-1.f,1.f), pack4(v1,s,-1.f,1.f),
                        pack4(v2,s,-1.f,1.f), pack4(v3,s,-1.f,1.f));
  *reinterpret_cast<uint4*>(wq + (size_t)i*16) = pk;
}

// ---------------- per-token activation quant (chunk) -> int8 + scale ----------------
__global__ void aquant8c(const float* __restrict__ x, char* __restrict__ xq,
                         float* __restrict__ s_a){
  int m = blockIdx.x, t = threadIdx.x;           // 256 thr, D=2048
  const float4* x4 = (const float4*)(x + (size_t)m*2048);
  float4 a = x4[t*2], b = x4[t*2+1];
  float va[8] = {a.x,a.y,a.z,a.w,b.x,b.y,b.z,b.w};
  float mx = 0.f;
  #pragma unroll
  for (int j=0;j<8;j++) mx = fmaxf(mx, fabsf(va[j]));
  #pragma unroll
  for (int o=1;o<64;o<<=1) mx = fmaxf(mx, __shfl_xor(mx, o, 64));
  __shared__ float wm[4];
  if ((t&63)==0) wm[t>>6] = mx;
  __syncthreads();
  mx = fmaxf(fmaxf(wm[0],wm[1]), fmaxf(wm[2],wm[3]));
  float s = 127.f / fmaxf(mx, EPSQ);
  if (t==0) s_a[m] = s;
  uint2 pk = make_uint2(pack4(a,s,-128.f,127.f), pack4(b,s,-128.f,127.f));
  *reinterpret_cast<uint2*>(xq + (size_t)m*2048 + t*8) = pk;
}

// ---------------- 256x256 i8 GEMM, 8 waves, 8-phase counted-vmcnt pipeline ----------------
// K-half = 64B; 4-slot LDS ring (slot = [A 256x64B | B 256x64B] = 32KB, ring = 128KB).
// Per K-half: 2 phases. ph0: stage A(h+2) [2 gload_lds] + ds_read bv[4]+av[0..3] ->
//   barrier -> lgkmcnt(0) -> 16 MFMA (fm0-3 x fn0-3). ph1: stage B(h+2) + av[4..7] ->
//   barrier -> lgkmcnt(0) -> 16 MFMA (fm4-7) -> vmcnt(4) [tail: vmcnt(0)] -> barrier.
// XOR swizzle chunk^((row>>1)&3): 2-way LDS conflict only (free). Deterministic i32
// atomicAdd epilogue (K-split over blockIdx.z; integer sums are order-independent).
__global__ __launch_bounds__(512,2) void gemm256(
    const char* __restrict__ A, int lda, const char* __restrict__ B, int ldb,
    int* __restrict__ C, int N, int Ks)
{
  __shared__ __align__(16) char sm[4*32768];
  const int tid = threadIdx.x, lane = tid & 63, w = tid >> 6;
  const int wr = w >> 2, wc = w & 3;                 // 2M x 4N waves
  const int m0 = blockIdx.y*256, n0 = blockIdx.x*256;
  const int kbase = blockIdx.z*Ks;

  i32x4 acc[8][4] = {};

  // stage geometry: chunk p = i*512+tid -> row = i*128+(tid>>2), phys col = tid&3,
  // logical col = (tid&3)^(((tid>>2)>>1)&3)  [row>>1 offsets by 64*i -> same mask]
  const int scl = (tid & 3) ^ ((tid >> 3) & 3);
  const char* gA = A + (size_t)(m0 + (tid>>2))*lda + kbase + scl*16;
  const char* gB = B + (size_t)(n0 + (tid>>2))*ldb + kbase + scl*16;
  const size_t a128 = (size_t)128*lda, b128 = (size_t)128*ldb;
  const int dst0 = tid*16;

  // read geometry
  const int frow = lane & 15, kb = lane >> 4;
  const int foff = (kb ^ ((frow >> 1) & 3))*16;
  int aoff[8], boff[4];
  #pragma unroll
  for (int f=0;f<8;f++) aoff[f] = (wr*128 + f*16 + frow)*64 + foff;
  #pragma unroll
  for (int f=0;f<4;f++) boff[f] = 16384 + (wc*64 + f*16 + frow)*64 + foff;

  auto stageA = [&](int slot, int kt){
    char* d = sm + slot*32768 + dst0;
    gload16(gA + kt, d); gload16(gA + kt + a128, d + 8192);
  };
  auto stageB = [&](int slot, int kt){
    char* d = sm + slot*32768 + 16384 + dst0;
    gload16(gB + kt, d); gload16(gB + kt + b128, d + 8192);
  };

  auto pair = [&](const int slot, const int ktH){
    const int nslot = (slot + 2) & 3;
    const bool st = (ktH + 128) < Ks;
    const char* base = sm + slot*32768;
    i32x4 av[4], bv[4];
    // ---- phase 0 ----
    if (st) stageA(nslot, ktH + 128);
    #pragma unroll
    for (int f=0;f<4;f++) bv[f] = *reinterpret_cast<const i32x4*>(base + boff[f]);
    #pragma unroll
    for (int f=0;f<4;f++) av[f] = *reinterpret_cast<const i32x4*>(base + aoff[f]);
    __builtin_amdgcn_s_barrier();
    asm volatile("s_waitcnt lgkmcnt(0)" ::: "memory");
    __builtin_amdgcn_sched_barrier(0);
    __builtin_amdgcn_s_setprio(1);
    #pragma unroll
    for (int fm=0;fm<4;fm++)
      #pragma unroll
      for (int fn=0;fn<4;fn++)
        acc[fm][fn] = __builtin_amdgcn_mfma_i32_16x16x64_i8(av[fm], bv[fn], acc[fm][fn], 0,0,0);
    __builtin_amdgcn_s_setprio(0);
    __builtin_amdgcn_s_barrier();
    // ---- phase 1 ----
    if (st) stageB(nslot, ktH + 128);
    #pragma unroll
    for (int f=0;f<4;f++) av[f] = *reinterpret_cast<const i32x4*>(base + aoff[4+f]);
    __builtin_amdgcn_s_barrier();
    asm volatile("s_waitcnt lgkmcnt(0)" ::: "memory");
    __builtin_amdgcn_sched_barrier(0);
    __builtin_amdgcn_s_setprio(1);
    #pragma unroll
    for (int fm=0;fm<4;fm++)
      #pragma unroll
      for (int fn=0;fn<4;fn++)
        acc[4+fm][fn] = __builtin_amdgcn_mfma_i32_16x16x64_i8(av[fm], bv[fn], acc[4+fm][fn], 0,0,0);
    __builtin_amdgcn_s_setprio(0);
    if (st) asm volatile("s_waitcnt vmcnt(4)" ::: "memory");
    else    asm volatile("s_waitcnt vmcnt(0)" ::: "memory");
    __builtin_amdgcn_s_barrier();
  };

  // prologue: halves 0,1 in flight (8 loads); retire half 0
  stageA(0, 0); stageB(0, 0); stageA(1, 64); stageB(1, 64);
  asm volatile("s_waitcnt vmcnt(4)" ::: "memory");
  __builtin_amdgcn_s_barrier();
  __builtin_amdgcn_sched_barrier(0);

  for (int kt = 0; kt < Ks; kt += 256){
    pair(0, kt);
    pair(1, kt + 64);
    pair(2, kt + 128);
    pair(3, kt + 192);
  }

  // epilogue: deterministic int32 accumulation
  const int cc = lane & 15, cr = (lane >> 4)*4;
  #pragma unroll
  for (int fm=0;fm<8;fm++){
    #pragma unroll
    for (int reg=0;reg<4;reg++){
      size_t r = (size_t)(m0 + wr*128 + fm*16 + cr + reg);
      #pragma unroll
      for (int fn=0;fn<4;fn++)
        atomicAdd(&C[r*N + n0 + wc*64 + fn*16 + cc], acc[fm][fn][reg]);
    }
  }
}

// ---------------- fused relu + rowMax + int8 requant over a full h row ----------------
__global__ void hquant2(const int* __restrict__ h, char* __restrict__ hq,
                        int* __restrict__ rowMax){
  int m = blockIdx.x, t = threadIdx.x;           // 256 thr, row of 8192 i32
  const int4* hp = (const int4*)(h + (size_t)m*8192);
  int4 v[8]; int mx = 0;
  #pragma unroll
  for (int j=0;j<8;j++){
    int4 q = hp[j*256 + t];
    q.x = q.x>0?q.x:0; q.y = q.y>0?q.y:0; q.z = q.z>0?q.z:0; q.w = q.w>0?q.w:0;
    v[j] = q;
    int a = q.x>q.y?q.x:q.y, b = q.z>q.w?q.z:q.w;
    mx = mx > (a>b?a:b) ? mx : (a>b?a:b);
  }
  #pragma unroll
  for (int o=1;o<64;o<<=1){ int s = __shfl_xor(mx, o, 64); mx = mx>s?mx:s; }
  __shared__ int wmx[4];
  if ((t&63)==0) wmx[t>>6] = mx;
  __syncthreads();
  { int a = wmx[0]>wmx[1]?wmx[0]:wmx[1], b = wmx[2]>wmx[3]?wmx[2]:wmx[3];
    mx = a>b?a:b; }
  if (t==0) rowMax[m] = mx;
  float rqv = (mx > 0) ? 127.f/(float)mx : 0.f;
  unsigned* o8 = (unsigned*)(hq + (size_t)m*8192);
  #pragma unroll
  for (int j=0;j<8;j++){
    int4 q = v[j];
    int a = (int)fminf(rintf((float)q.x*rqv),127.f);
    int b = (int)fminf(rintf((float)q.y*rqv),127.f);
    int c = (int)fminf(rintf((float)q.z*rqv),127.f);
    int d = (int)fminf(rintf((float)q.w*rqv),127.f);
    o8[j*256 + t] = (unsigned)((a&255)|((b&255)<<8)|((c&255)<<16)|((d&255)<<24));
  }
}

// ---------------- int32 accum -> f32 out, per-row scale (in-place) ----------------
__global__ void convert_out(float* __restrict__ out, const int* __restrict__ rowMax,
                            const float* __restrict__ s_a, const float* __restrict__ scalebuf){
  int m = blockIdx.x, t = threadIdx.x;
  int Mi = rowMax[m];
  float maxref = (float)Mi / (s_a[m]*scalebuf[0]);
  float inv2 = fmaxf(maxref, EPSQ) / (127.f*scalebuf[1]);
  int* p = (int*)(out + (size_t)m*2048);
  int4 a = ((const int4*)p)[t*2], b = ((const int4*)p)[t*2+1];
  float4 fa = make_float4((float)a.x*inv2, (float)a.y*inv2, (float)a.z*inv2, (float)a.w*inv2);
  float4 fb = make_float4((float)b.x*inv2, (float)b.y*inv2, (float)b.z*inv2, (float)b.w*inv2);
  ((float4*)p)[t*2] = fa; ((float4*)p)[t*2+1] = fb;
}

extern "C" void kernel_launch(void* const* d_in, const int* in_sizes, int n_in,
                              void* d_out, int out_size, void* d_ws, size_t ws_size,
                              hipStream_t stream){
  const float* x  = (const float*)d_in[0];
  const float* w1 = (const float*)d_in[1];
  const float* w2 = (const float*)d_in[2];
  float* out = (float*)d_out;

  const int DIM = 2048, INNER = 8192, MTOK = 8192;
  const size_t nW = (size_t)INNER*DIM;   // 16 MB int8 per weight

  char* ws = (char*)d_ws; size_t off = 0;
  auto alloc = [&](size_t n)->char*{ char* p = ws+off; off = (off+n+255) & ~(size_t)255; return p; };

  float*  s_a     = (float*)alloc((size_t)MTOK*4);
  int*    rowMax  = (int*)  alloc((size_t)MTOK*4);
  float*  scalebuf= (float*)alloc(256);
  double* partial = (double*)alloc(2048*8);
  char*   w1q     = alloc(nW);
  char*   w2q     = alloc(nW);

  // per-chunk: a8c (Mc x 2048 i8) + h_i32 (Mc x 8192 i32) + hq (Mc x 8192 i8)
  int Mc = 0;
  for (int m = 2048; m >= 256; m >>= 1)
    if (off + (size_t)m*(2048 + 8192*4 + 8192) + 4096 <= ws_size){ Mc = m; break; }
  if (!Mc) return;
  char* a8c  = alloc((size_t)Mc*2048);
  int*  h32i = (int*)alloc((size_t)Mc*8192*4);
  char* hq   = alloc((size_t)Mc*8192);

  absmean_partial<<<1024,256,0,stream>>>(w1, (int)(nW/4), partial);
  absmean_partial<<<1024,256,0,stream>>>(w2, (int)(nW/4), partial+1024);
  finalize_scales<<<1,256,0,stream>>>(partial, scalebuf, 1.0/(double)nW);
  wquant8<<<(int)(nW/16/256),256,0,stream>>>(w1, w1q, scalebuf, 0);
  wquant8<<<(int)(nW/16/256),256,0,stream>>>(w2, w2q, scalebuf, 1);

  const int z1 = DIM/Mc > 0 ? DIM/Mc : 1;       // GEMM1 K-split so grid = 256 blocks
  const int z2 = INNER/Mc;                      // GEMM2 K-split so grid = 256 blocks
  const int Ks1 = DIM/z1, Ks2 = INNER/z2;       // both = Mc (multiples of 256)

  for (int ch = 0; ch < MTOK; ch += Mc){
    aquant8c<<<Mc,256,0,stream>>>(x + (size_t)ch*DIM, a8c, s_a + ch);
    hipMemsetAsync(h32i, 0, (size_t)Mc*INNER*4, stream);
    gemm256<<<dim3(INNER/256, Mc/256, z1),512,0,stream>>>(
        a8c, DIM, w1q, DIM, h32i, INNER, Ks1);
    hquant2<<<Mc,256,0,stream>>>(h32i, hq, rowMax + ch);
    hipMemsetAsync(out + (size_t)ch*DIM, 0, (size_t)Mc*DIM*4, stream);
    gemm256<<<dim3(DIM/256, Mc/256, z2),512,0,stream>>>(
        hq, INNER, w2q, INNER, (int*)(out + (size_t)ch*DIM), DIM, Ks2);
    convert_out<<<Mc,256,0,stream>>>(out + (size_t)ch*DIM, rowMax + ch, s_a + ch, scalebuf);
  }
}

// Round 9
// 488.659 us; speedup vs baseline: 1.6634x; 1.6634x over previous
//
#include <hip/hip_runtime.h>
#include <hip/hip_bf16.h>
#include <stdint.h>

#define EPSQ 1e-5f

typedef int i32x4 __attribute__((ext_vector_type(4)));

__device__ inline void gload16(const void* g, void* l){
  __builtin_amdgcn_global_load_lds((const __attribute__((address_space(1))) unsigned int*)g,
                                   (__attribute__((address_space(3))) unsigned int*)l, 16, 0, 0);
}

__device__ inline unsigned pack4(float4 v, float s, float lo, float hi){
  int a = (int)fminf(fmaxf(rintf(v.x*s), lo), hi);
  int b = (int)fminf(fmaxf(rintf(v.y*s), lo), hi);
  int c = (int)fminf(fmaxf(rintf(v.z*s), lo), hi);
  int d = (int)fminf(fmaxf(rintf(v.w*s), lo), hi);
  return (unsigned)((a&255)|((b&255)<<8)|((c&255)<<16)|((d&255)<<24));
}

// ---------------- mean|w| two-stage deterministic reduction ----------------
__global__ void absmean_partial(const float* __restrict__ w, int n4, double* __restrict__ partial){
  const float4* w4 = (const float4*)w;
  double s = 0.0;
  int idx = blockIdx.x*blockDim.x + threadIdx.x;
  int stride = gridDim.x*blockDim.x;
  for (int i = idx; i < n4; i += stride){
    float4 v = w4[i];
    s += (double)(fabsf(v.x)+fabsf(v.y)+fabsf(v.z)+fabsf(v.w));
  }
  __shared__ double sm[256];
  sm[threadIdx.x] = s; __syncthreads();
  for (int o=128;o>0;o>>=1){ if (threadIdx.x<o) sm[threadIdx.x]+=sm[threadIdx.x+o]; __syncthreads(); }
  if (threadIdx.x==0) partial[blockIdx.x] = sm[0];
}

__global__ void finalize_scales(const double* __restrict__ partial, float* __restrict__ scalebuf, double inv_n){
  __shared__ double sm[256];
  int t = threadIdx.x;
  double s1 = partial[t] + partial[t+256] + partial[t+512] + partial[t+768];
  sm[t]=s1; __syncthreads();
  for(int o=128;o>0;o>>=1){ if(t<o) sm[t]+=sm[t+o]; __syncthreads(); }
  double m1 = sm[0];
  __syncthreads();
  double s2 = partial[1024+t]+partial[1280+t]+partial[1536+t]+partial[1792+t];
  sm[t]=s2; __syncthreads();
  for(int o=128;o>0;o>>=1){ if(t<o) sm[t]+=sm[t+o]; __syncthreads(); }
  if (t==0){
    scalebuf[0] = 1.0f / fmaxf((float)(m1*inv_n),    EPSQ);   // s_w1
    scalebuf[1] = 1.0f / fmaxf((float)(sm[0]*inv_n), EPSQ);   // s_w2
  }
}

// ---------------- ternary weight quantization -> int8 {-1,0,1} ----------------
__global__ void wquant8(const float* __restrict__ w, char* __restrict__ wq,
                        const float* __restrict__ scalebuf, int which){
  int i = blockIdx.x*256 + threadIdx.x;
  float s = scalebuf[which];
  const float4* w4 = (const float4*)w;
  float4 v0 = w4[(size_t)i*4], v1 = w4[(size_t)i*4+1], v2 = w4[(size_t)i*4+2], v3 = w4[(size_t)i*4+3];
  uint4 pk = make_uint4(pack4(v0,s,-1.f,1.f), pack4(v1,s,-1.f,1.f),
                        pack4(v2,s,-1.f,1.f), pack4(v3,s,-1.f,1.f));
  *reinterpret_cast<uint4*>(wq + (size_t)i*16) = pk;
}

// ---------------- per-token activation quant (chunk) -> int8 + scale + rowMax=0 ----------------
__global__ void aquant8c(const float* __restrict__ x, char* __restrict__ xq,
                         float* __restrict__ s_a, int* __restrict__ rowMax){
  int m = blockIdx.x, t = threadIdx.x;           // 256 thr, D=2048
  if (t==0) rowMax[m] = 0;
  const float4* x4 = (const float4*)(x + (size_t)m*2048);
  float4 a = x4[t*2], b = x4[t*2+1];
  float va[8] = {a.x,a.y,a.z,a.w,b.x,b.y,b.z,b.w};
  float mx = 0.f;
  #pragma unroll
  for (int j=0;j<8;j++) mx = fmaxf(mx, fabsf(va[j]));
  #pragma unroll
  for (int o=1;o<64;o<<=1) mx = fmaxf(mx, __shfl_xor(mx, o, 64));
  __shared__ float wm[4];
  if ((t&63)==0) wm[t>>6] = mx;
  __syncthreads();
  mx = fmaxf(fmaxf(wm[0],wm[1]), fmaxf(wm[2],wm[3]));
  float s = 127.f / fmaxf(mx, EPSQ);
  if (t==0) s_a[m] = s;
  uint2 pk = make_uint2(pack4(a,s,-128.f,127.f), pack4(b,s,-128.f,127.f));
  *reinterpret_cast<uint2*>(xq + (size_t)m*2048 + t*8) = pk;
}

// ---------------- 256x128 i8 GEMM, 8 waves, ring-3 counted-vmcnt 2x16-MFMA phases ----------------
// Tile 256M x 128N, BK=128B. LDS slot = [A 256x128B | B 128x128B] = 48KB, 3 slots = 144KB.
// 8 waves as 4M x 2N, per-wave 64x64 = acc[4][4], 32 MFMA / K-step (2 phases of 16).
// Per step: ph0 {8 ds_read + stageA(t+2) 4 glds -> bar -> lgkm0 -> 16 MFMA} ;
//           ph1 {8 ds_read + stageB(t+2) 2 glds -> bar -> lgkm0 -> 16 MFMA -> vmcnt(6) -> bar}.
// vmcnt(6) keeps next-next tile's 6 loads in flight (never drains mid-loop).
// lda == ldb == Ks for both GEMMs (A rows span exactly K).
// EPI 0: h16 = min(relu,65535), per-row max -> rowMax (LDS + global atomicMax). N=8192.
// EPI 1: out f32 = acc * inv2(row) fused from rowMax/s_a/scalebuf. N=2048. Plain stores.
template<int EPI>
__global__ __launch_bounds__(512,2) void gemmK(
    const char* __restrict__ A, const char* __restrict__ B, void* __restrict__ Cv,
    int Ks, int moff, int* __restrict__ rowMax, const float* __restrict__ s_a,
    const float* __restrict__ scalebuf)
{
  __shared__ __align__(16) char sm[3*49152 + 1024];
  int* smax = (int*)(sm + 3*49152);
  const int tid = threadIdx.x, lane = tid & 63, w = tid >> 6;
  const int wr = w >> 1, wc = w & 1;               // 4M x 2N waves
  const int n0 = blockIdx.x*128, m0 = blockIdx.y*256;
  const int steps = Ks >> 7;

  i32x4 acc[4][4] = {};

  // staging: thread covers rows trow + i*64; phys chunk tid&7 holds logical (tid&7)^(row&7)
  const int trow = tid >> 3;
  const int scl  = (tid & 7) ^ (trow & 7);
  const char* gA = A + (size_t)(m0 + trow)*Ks + scl*16;
  const char* gB = B + (size_t)(n0 + trow)*Ks + scl*16;
  const int dA = tid*16;

  auto stA = [&](int sbase, int kt){
    #pragma unroll
    for (int i=0;i<4;i++)
      gload16(gA + kt + (size_t)(i*64)*Ks, sm + sbase + i*8192 + dA);
  };
  auto stB = [&](int sbase, int kt){
    #pragma unroll
    for (int i=0;i<2;i++)
      gload16(gB + kt + (size_t)(i*64)*Ks, sm + sbase + 32768 + i*8192 + dA);
  };

  // read-side offsets (XOR swizzle: logical chunk ^ (row&7))
  const int frow = lane & 15, kb = lane >> 4;
  int aoff[2][4], boff[2][4];
  #pragma unroll
  for (int kh=0;kh<2;kh++){
    #pragma unroll
    for (int f=0;f<4;f++){
      int ra = wr*64 + f*16 + frow;
      aoff[kh][f] = ra*128 + ((((kh<<2)|kb) ^ (ra&7))<<4);
      int rb = wc*64 + f*16 + frow;
      boff[kh][f] = 32768 + rb*128 + ((((kh<<2)|kb) ^ (rb&7))<<4);
    }
  }

  auto kstep = [&](int slot, int t, int mode){   // mode 0: stage t+2 + vmcnt(6); 1: vmcnt(0); 2: none
    const char* base = sm + slot*49152;
    int ns = slot + 2; if (ns >= 3) ns -= 3;
    i32x4 av[4], bv[4];
    // ---- phase 0 (k-half 0) ----
    #pragma unroll
    for (int f=0;f<4;f++){
      av[f] = *reinterpret_cast<const i32x4*>(base + aoff[0][f]);
      bv[f] = *reinterpret_cast<const i32x4*>(base + boff[0][f]);
    }
    if (mode == 0) stA(ns*49152, (t+2)<<7);
    __builtin_amdgcn_s_barrier();
    asm volatile("s_waitcnt lgkmcnt(0)" ::: "memory");
    __builtin_amdgcn_sched_barrier(0);
    __builtin_amdgcn_s_setprio(1);
    #pragma unroll
    for (int fm=0;fm<4;fm++)
      #pragma unroll
      for (int fn=0;fn<4;fn++)
        acc[fm][fn] = __builtin_amdgcn_mfma_i32_16x16x64_i8(av[fm], bv[fn], acc[fm][fn], 0,0,0);
    __builtin_amdgcn_s_setprio(0);
    __builtin_amdgcn_s_barrier();
    // ---- phase 1 (k-half 1) ----
    #pragma unroll
    for (int f=0;f<4;f++){
      av[f] = *reinterpret_cast<const i32x4*>(base + aoff[1][f]);
      bv[f] = *reinterpret_cast<const i32x4*>(base + boff[1][f]);
    }
    if (mode == 0) stB(ns*49152, (t+2)<<7);
    __builtin_amdgcn_s_barrier();
    asm volatile("s_waitcnt lgkmcnt(0)" ::: "memory");
    __builtin_amdgcn_sched_barrier(0);
    __builtin_amdgcn_s_setprio(1);
    #pragma unroll
    for (int fm=0;fm<4;fm++)
      #pragma unroll
      for (int fn=0;fn<4;fn++)
        acc[fm][fn] = __builtin_amdgcn_mfma_i32_16x16x64_i8(av[fm], bv[fn], acc[fm][fn], 0,0,0);
    __builtin_amdgcn_s_setprio(0);
    if (mode == 0)      asm volatile("s_waitcnt vmcnt(6)" ::: "memory");
    else if (mode == 1) asm volatile("s_waitcnt vmcnt(0)" ::: "memory");
    __builtin_amdgcn_s_barrier();
  };

  // prologue: tiles 0,1 in flight (12 loads); retire tile 0
  stA(0, 0); stB(0, 0); stA(49152, 128); stB(49152, 128);
  asm volatile("s_waitcnt vmcnt(6)" ::: "memory");
  __builtin_amdgcn_s_barrier();
  __builtin_amdgcn_sched_barrier(0);

  int slot = 0;
  for (int t = 0; t < steps; ++t){
    int mode = (t+2 < steps) ? 0 : ((t+1 < steps) ? 1 : 2);
    kstep(slot, t, mode);
    slot = (slot == 2) ? 0 : slot + 1;
  }

  // ---- epilogue ----
  const int cc = lane & 15, cr = (lane >> 4)*4;
  if (EPI == 0){
    if (tid < 256) smax[tid] = 0;
    __syncthreads();
    ushort* C16 = (ushort*)Cv;
    #pragma unroll
    for (int fm=0;fm<4;fm++){
      #pragma unroll
      for (int reg=0;reg<4;reg++){
        int rl = wr*64 + fm*16 + cr + reg;
        size_t r = (size_t)(m0 + rl);
        int rmax = 0;
        #pragma unroll
        for (int fn=0;fn<4;fn++){
          int v = acc[fm][fn][reg]; v = v > 0 ? v : 0;       // fused relu, exact int
          C16[r*8192 + n0 + wc*64 + fn*16 + cc] = (ushort)(v > 65535 ? 65535 : v);
          rmax = v > rmax ? v : rmax;
        }
        atomicMax(&smax[rl], rmax);
      }
    }
    __syncthreads();
    if (tid < 256) atomicMax(&rowMax[m0 + tid], smax[tid]);
  } else {
    float* out = (float*)Cv;
    float sw1 = scalebuf[0], sw2 = scalebuf[1];
    #pragma unroll
    for (int fm=0;fm<4;fm++){
      #pragma unroll
      for (int reg=0;reg<4;reg++){
        int rl = wr*64 + fm*16 + cr + reg;
        size_t r = (size_t)(moff + m0 + rl);
        int Mi = rowMax[r];
        float maxref = (float)Mi / (s_a[r]*sw1);
        float inv2 = fmaxf(maxref, EPSQ) / (127.f*sw2);
        #pragma unroll
        for (int fn=0;fn<4;fn++)
          out[r*2048 + n0 + wc*64 + fn*16 + cc] = (float)acc[fm][fn][reg] * inv2;
      }
    }
  }
}

// ---------------- h16 -> int8 requant (rq = 127/Mi, exact integer domain) ----------------
__global__ void hquant(const ushort* __restrict__ h16, char* __restrict__ hq,
                       const int* __restrict__ rowMax){
  int m = blockIdx.y;
  int Mi = rowMax[m];
  float rqv = (Mi > 0) ? 127.f/(float)Mi : 0.f;
  size_t base = (size_t)m*8192 + blockIdx.x*2048 + threadIdx.x*8;
  uint4 pk = *reinterpret_cast<const uint4*>(h16 + base);
  unsigned u[4] = {pk.x, pk.y, pk.z, pk.w};
  unsigned o[2] = {0,0};
  #pragma unroll
  for (int j=0;j<8;j++){
    float h = (float)(u[j>>1] >> ((j&1)*16) & 0xffff);
    int q = (int)fminf(rintf(h*rqv), 127.f);            // h >= 0
    o[j>>2] |= (unsigned)(q & 255) << ((j&3)*8);
  }
  *reinterpret_cast<uint2*>(hq + base) = make_uint2(o[0], o[1]);
}

extern "C" void kernel_launch(void* const* d_in, const int* in_sizes, int n_in,
                              void* d_out, int out_size, void* d_ws, size_t ws_size,
                              hipStream_t stream){
  const float* x  = (const float*)d_in[0];
  const float* w1 = (const float*)d_in[1];
  const float* w2 = (const float*)d_in[2];
  float* out = (float*)d_out;

  const int MTOK = 8192, Mc = 1024;
  const size_t nW = (size_t)8192*2048;   // 16 MiB int8 per weight

  char* ws = (char*)d_ws; size_t off = 0;
  auto alloc = [&](size_t n)->char*{ char* p = ws+off; off = (off+n+255) & ~(size_t)255; return p; };

  float*  s_a     = (float*)alloc((size_t)MTOK*4);
  int*    rowMax  = (int*)  alloc((size_t)MTOK*4);
  float*  scalebuf= (float*)alloc(256);
  double* partial = (double*)alloc(2048*8);
  char*   w1q     = alloc(nW);
  char*   shared  = alloc(nW);                  // h16 (Mc x 8192 u16 = 16MB) aliases w2q (16MB)
  char*   a8c     = alloc((size_t)Mc*2048);
  ushort* h16     = (ushort*)shared;

  // hq holds one M-segment of int8 h: pick largest segment that fits
  int hqM = 0;
  for (int m = 4096; m >= 1024; m >>= 1)
    if (off + (size_t)m*8192 <= ws_size){ hqM = m; break; }
  if (!hqM) return;
  char* hq = alloc((size_t)hqM*8192);

  absmean_partial<<<1024,256,0,stream>>>(w1, (int)(nW/4), partial);
  absmean_partial<<<1024,256,0,stream>>>(w2, (int)(nW/4), partial+1024);
  finalize_scales<<<1,256,0,stream>>>(partial, scalebuf, 1.0/(double)nW);
  wquant8<<<(int)(nW/16/256),256,0,stream>>>(w1, w1q, scalebuf, 0);

  for (int s = 0; s < MTOK/hqM; ++s){
    for (int c = 0; c < hqM/Mc; ++c){
      int ch = s*hqM + c*Mc;
      aquant8c<<<Mc,256,0,stream>>>(x + (size_t)ch*2048, a8c, s_a + ch, rowMax + ch);
      gemmK<0><<<dim3(64, Mc/256),512,0,stream>>>(
          a8c, w1q, h16, 2048, 0, rowMax + ch, nullptr, scalebuf);
      hquant<<<dim3(4, Mc),256,0,stream>>>(h16, hq + (size_t)c*Mc*8192, rowMax + ch);
    }
    // h16 region now dead for this segment -> quantize w2 into it
    wquant8<<<(int)(nW/16/256),256,0,stream>>>(w2, shared, scalebuf, 1);
    gemmK<1><<<dim3(16, hqM/256),512,0,stream>>>(
        hq, shared, out, 8192, s*hqM, rowMax, s_a, scalebuf);
  }
}

// Round 10
// 445.877 us; speedup vs baseline: 1.8230x; 1.0960x over previous
//
#include <hip/hip_runtime.h>
#include <hip/hip_bf16.h>
#include <stdint.h>

#define EPSQ 1e-5f

typedef int i32x4 __attribute__((ext_vector_type(4)));

__device__ inline void gload16(const void* g, void* l){
  __builtin_amdgcn_global_load_lds((const __attribute__((address_space(1))) unsigned int*)g,
                                   (__attribute__((address_space(3))) unsigned int*)l, 16, 0, 0);
}

__device__ inline unsigned pack4(float4 v, float s, float lo, float hi){
  int a = (int)fminf(fmaxf(rintf(v.x*s), lo), hi);
  int b = (int)fminf(fmaxf(rintf(v.y*s), lo), hi);
  int c = (int)fminf(fmaxf(rintf(v.z*s), lo), hi);
  int d = (int)fminf(fmaxf(rintf(v.w*s), lo), hi);
  return (unsigned)((a&255)|((b&255)<<8)|((c&255)<<16)|((d&255)<<24));
}

// ---------------- mean|w| over BOTH weights, one dispatch ----------------
__global__ void absmean2(const float* __restrict__ w1, const float* __restrict__ w2,
                         int n4, double* __restrict__ partial){
  const int half = blockIdx.x >> 10;             // 0: w1, 1: w2
  const float4* w4 = (const float4*)(half ? w2 : w1);
  double s = 0.0;
  int idx = (blockIdx.x & 1023)*blockDim.x + threadIdx.x;
  int stride = 1024*blockDim.x;
  for (int i = idx; i < n4; i += stride){
    float4 v = w4[i];
    s += (double)(fabsf(v.x)+fabsf(v.y)+fabsf(v.z)+fabsf(v.w));
  }
  __shared__ double sm[256];
  sm[threadIdx.x] = s; __syncthreads();
  for (int o=128;o>0;o>>=1){ if (threadIdx.x<o) sm[threadIdx.x]+=sm[threadIdx.x+o]; __syncthreads(); }
  if (threadIdx.x==0) partial[blockIdx.x] = sm[0];
}

__global__ void finalize_scales(const double* __restrict__ partial, float* __restrict__ scalebuf, double inv_n){
  __shared__ double sm[256];
  int t = threadIdx.x;
  double s1 = partial[t] + partial[t+256] + partial[t+512] + partial[t+768];
  sm[t]=s1; __syncthreads();
  for(int o=128;o>0;o>>=1){ if(t<o) sm[t]+=sm[t+o]; __syncthreads(); }
  double m1 = sm[0];
  __syncthreads();
  double s2 = partial[1024+t]+partial[1280+t]+partial[1536+t]+partial[1792+t];
  sm[t]=s2; __syncthreads();
  for(int o=128;o>0;o>>=1){ if(t<o) sm[t]+=sm[t+o]; __syncthreads(); }
  if (t==0){
    scalebuf[0] = 1.0f / fmaxf((float)(m1*inv_n),    EPSQ);   // s_w1
    scalebuf[1] = 1.0f / fmaxf((float)(sm[0]*inv_n), EPSQ);   // s_w2
  }
}

// ---------------- ternary weight quantization -> int8 {-1,0,1} ----------------
__global__ void wquant8(const float* __restrict__ w, char* __restrict__ wq,
                        const float* __restrict__ scalebuf, int which){
  int i = blockIdx.x*256 + threadIdx.x;
  float s = scalebuf[which];
  const float4* w4 = (const float4*)w;
  float4 v0 = w4[(size_t)i*4], v1 = w4[(size_t)i*4+1], v2 = w4[(size_t)i*4+2], v3 = w4[(size_t)i*4+3];
  uint4 pk = make_uint4(pack4(v0,s,-1.f,1.f), pack4(v1,s,-1.f,1.f),
                        pack4(v2,s,-1.f,1.f), pack4(v3,s,-1.f,1.f));
  *reinterpret_cast<uint4*>(wq + (size_t)i*16) = pk;
}

// ---------------- per-token activation quant (chunk) -> int8 + scale + rowMax=0 ----------------
__global__ void aquant8c(const float* __restrict__ x, char* __restrict__ xq,
                         float* __restrict__ s_a, int* __restrict__ rowMax){
  int m = blockIdx.x, t = threadIdx.x;           // 256 thr, D=2048
  if (t==0) rowMax[m] = 0;
  const float4* x4 = (const float4*)(x + (size_t)m*2048);
  float4 a = x4[t*2], b = x4[t*2+1];
  float va[8] = {a.x,a.y,a.z,a.w,b.x,b.y,b.z,b.w};
  float mx = 0.f;
  #pragma unroll
  for (int j=0;j<8;j++) mx = fmaxf(mx, fabsf(va[j]));
  #pragma unroll
  for (int o=1;o<64;o<<=1) mx = fmaxf(mx, __shfl_xor(mx, o, 64));
  __shared__ float wm[4];
  if ((t&63)==0) wm[t>>6] = mx;
  __syncthreads();
  mx = fmaxf(fmaxf(wm[0],wm[1]), fmaxf(wm[2],wm[3]));
  float s = 127.f / fmaxf(mx, EPSQ);
  if (t==0) s_a[m] = s;
  uint2 pk = make_uint2(pack4(a,s,-128.f,127.f), pack4(b,s,-128.f,127.f));
  *reinterpret_cast<uint2*>(xq + (size_t)m*2048 + t*8) = pk;
}

// ---------------- 256x128 i8 GEMM, 8 waves, ring-3 counted-vmcnt, STATIC slots ----------------
// Identical schedule to R9 (2x16-MFMA phases, vmcnt(6), setprio, XOR swizzle) but the
// ring slot is a compile-time literal everywhere (triples + unrolled tail), so all 16
// LDS read addresses per slot hoist out of the loop (R9: runtime slot -> per-read v_add,
// VALUBusy 20%). STEPS = K/128 is a template parameter (16 GEMM1 / 64 GEMM2).
// EPI 0: h16 = min(relu,65535), per-row max -> rowMax. EPI 1: out f32 = acc * inv2(row).
template<int EPI, int STEPS>
__global__ __launch_bounds__(512,2) void gemmK(
    const char* __restrict__ A, const char* __restrict__ B, void* __restrict__ Cv,
    int moff, int* __restrict__ rowMax, const float* __restrict__ s_a,
    const float* __restrict__ scalebuf)
{
  const int Ks = STEPS << 7;
  __shared__ __align__(16) char sm[3*49152 + 1024];
  int* smax = (int*)(sm + 3*49152);
  const int tid = threadIdx.x, lane = tid & 63, w = tid >> 6;
  const int wr = w >> 1, wc = w & 1;               // 4M x 2N waves
  const int n0 = blockIdx.x*128, m0 = blockIdx.y*256;

  i32x4 acc[4][4] = {};

  // staging: thread covers rows trow + i*64; phys chunk tid&7 holds logical (tid&7)^(row&7)
  const int trow = tid >> 3;
  const int scl  = (tid & 7) ^ (trow & 7);
  const char* gA = A + (size_t)(m0 + trow)*Ks + scl*16;
  const char* gB = B + (size_t)(n0 + trow)*Ks + scl*16;
  const int dA = tid*16;

  auto stA = [&](int sbase, int kt){
    #pragma unroll
    for (int i=0;i<4;i++)
      gload16(gA + kt + (size_t)(i*64)*Ks, sm + sbase + i*8192 + dA);
  };
  auto stB = [&](int sbase, int kt){
    #pragma unroll
    for (int i=0;i<2;i++)
      gload16(gB + kt + (size_t)(i*64)*Ks, sm + sbase + 32768 + i*8192 + dA);
  };

  // read-side offsets (XOR swizzle: logical chunk ^ (row&7))
  const int frow = lane & 15, kb = lane >> 4;
  int aoff[2][4], boff[2][4];
  #pragma unroll
  for (int kh=0;kh<2;kh++){
    #pragma unroll
    for (int f=0;f<4;f++){
      int ra = wr*64 + f*16 + frow;
      aoff[kh][f] = ra*128 + ((((kh<<2)|kb) ^ (ra&7))<<4);
      int rb = wc*64 + f*16 + frow;
      boff[kh][f] = 32768 + rb*128 + ((((kh<<2)|kb) ^ (rb&7))<<4);
    }
  }

  auto kstep = [&](const int slot, int t, const int mode){
    // slot and mode are compile-time literals at every call site.
    const char* base = sm + slot*49152;
    const int ns = (slot + 2 >= 3) ? slot - 1 : slot + 2;
    i32x4 av[4], bv[4];
    // ---- phase 0 (k-half 0) ----
    #pragma unroll
    for (int f=0;f<4;f++){
      av[f] = *reinterpret_cast<const i32x4*>(base + aoff[0][f]);
      bv[f] = *reinterpret_cast<const i32x4*>(base + boff[0][f]);
    }
    if (mode == 0) stA(ns*49152, (t+2)<<7);
    __builtin_amdgcn_s_barrier();
    asm volatile("s_waitcnt lgkmcnt(0)" ::: "memory");
    __builtin_amdgcn_sched_barrier(0);
    __builtin_amdgcn_s_setprio(1);
    #pragma unroll
    for (int fm=0;fm<4;fm++)
      #pragma unroll
      for (int fn=0;fn<4;fn++)
        acc[fm][fn] = __builtin_amdgcn_mfma_i32_16x16x64_i8(av[fm], bv[fn], acc[fm][fn], 0,0,0);
    __builtin_amdgcn_s_setprio(0);
    __builtin_amdgcn_s_barrier();
    // ---- phase 1 (k-half 1) ----
    #pragma unroll
    for (int f=0;f<4;f++){
      av[f] = *reinterpret_cast<const i32x4*>(base + aoff[1][f]);
      bv[f] = *reinterpret_cast<const i32x4*>(base + boff[1][f]);
    }
    if (mode == 0) stB(ns*49152, (t+2)<<7);
    __builtin_amdgcn_s_barrier();
    asm volatile("s_waitcnt lgkmcnt(0)" ::: "memory");
    __builtin_amdgcn_sched_barrier(0);
    __builtin_amdgcn_s_setprio(1);
    #pragma unroll
    for (int fm=0;fm<4;fm++)
      #pragma unroll
      for (int fn=0;fn<4;fn++)
        acc[fm][fn] = __builtin_amdgcn_mfma_i32_16x16x64_i8(av[fm], bv[fn], acc[fm][fn], 0,0,0);
    __builtin_amdgcn_s_setprio(0);
    if (mode == 0)      asm volatile("s_waitcnt vmcnt(6)" ::: "memory");
    else if (mode == 1) asm volatile("s_waitcnt vmcnt(0)" ::: "memory");
    __builtin_amdgcn_s_barrier();
  };

  // prologue: tiles 0,1 in flight (12 loads); retire tile 0
  stA(0, 0); stB(0, 0); stA(49152, 128); stB(49152, 128);
  asm volatile("s_waitcnt vmcnt(6)" ::: "memory");
  __builtin_amdgcn_s_barrier();
  __builtin_amdgcn_sched_barrier(0);

  // STEPS % 3 == 1 for both instantiations: (STEPS-4)/3 static triples + 4-step tail.
  constexpr int TRIPLES = (STEPS - 4) / 3;
  for (int tt = 0; tt < TRIPLES; ++tt){
    int t = tt*3;
    kstep(0, t,   0);
    kstep(1, t+1, 0);
    kstep(2, t+2, 0);
  }
  kstep(0, STEPS-4, 0);
  kstep(1, STEPS-3, 0);
  kstep(2, STEPS-2, 1);
  kstep(0, STEPS-1, 2);

  // ---- epilogue ----
  const int cc = lane & 15, cr = (lane >> 4)*4;
  if (EPI == 0){
    if (tid < 256) smax[tid] = 0;
    __syncthreads();
    ushort* C16 = (ushort*)Cv;
    #pragma unroll
    for (int fm=0;fm<4;fm++){
      #pragma unroll
      for (int reg=0;reg<4;reg++){
        int rl = wr*64 + fm*16 + cr + reg;
        size_t r = (size_t)(m0 + rl);
        int rmax = 0;
        #pragma unroll
        for (int fn=0;fn<4;fn++){
          int v = acc[fm][fn][reg]; v = v > 0 ? v : 0;       // fused relu, exact int
          C16[r*8192 + n0 + wc*64 + fn*16 + cc] = (ushort)(v > 65535 ? 65535 : v);
          rmax = v > rmax ? v : rmax;
        }
        atomicMax(&smax[rl], rmax);
      }
    }
    __syncthreads();
    if (tid < 256) atomicMax(&rowMax[m0 + tid], smax[tid]);
  } else {
    float* out = (float*)Cv;
    float sw1 = scalebuf[0], sw2 = scalebuf[1];
    #pragma unroll
    for (int fm=0;fm<4;fm++){
      #pragma unroll
      for (int reg=0;reg<4;reg++){
        int rl = wr*64 + fm*16 + cr + reg;
        size_t r = (size_t)(moff + m0 + rl);
        int Mi = rowMax[r];
        float maxref = (float)Mi / (s_a[r]*sw1);
        float inv2 = fmaxf(maxref, EPSQ) / (127.f*sw2);
        #pragma unroll
        for (int fn=0;fn<4;fn++)
          out[r*2048 + n0 + wc*64 + fn*16 + cc] = (float)acc[fm][fn][reg] * inv2;
      }
    }
  }
}

// ---------------- h16 -> int8 requant (rq = 127/Mi, exact integer domain) ----------------
__global__ void hquant(const ushort* __restrict__ h16, char* __restrict__ hq,
                       const int* __restrict__ rowMax){
  int m = blockIdx.y;
  int Mi = rowMax[m];
  float rqv = (Mi > 0) ? 127.f/(float)Mi : 0.f;
  size_t base = (size_t)m*8192 + blockIdx.x*2048 + threadIdx.x*8;
  uint4 pk = *reinterpret_cast<const uint4*>(h16 + base);
  unsigned u[4] = {pk.x, pk.y, pk.z, pk.w};
  unsigned o[2] = {0,0};
  #pragma unroll
  for (int j=0;j<8;j++){
    float h = (float)(u[j>>1] >> ((j&1)*16) & 0xffff);
    int q = (int)fminf(rintf(h*rqv), 127.f);            // h >= 0
    o[j>>2] |= (unsigned)(q & 255) << ((j&3)*8);
  }
  *reinterpret_cast<uint2*>(hq + base) = make_uint2(o[0], o[1]);
}

extern "C" void kernel_launch(void* const* d_in, const int* in_sizes, int n_in,
                              void* d_out, int out_size, void* d_ws, size_t ws_size,
                              hipStream_t stream){
  const float* x  = (const float*)d_in[0];
  const float* w1 = (const float*)d_in[1];
  const float* w2 = (const float*)d_in[2];
  float* out = (float*)d_out;

  const int MTOK = 8192, Mc = 1024;
  const size_t nW = (size_t)8192*2048;   // 16 MiB int8 per weight

  char* ws = (char*)d_ws; size_t off = 0;
  auto alloc = [&](size_t n)->char*{ char* p = ws+off; off = (off+n+255) & ~(size_t)255; return p; };

  float*  s_a     = (float*)alloc((size_t)MTOK*4);
  int*    rowMax  = (int*)  alloc((size_t)MTOK*4);
  float*  scalebuf= (float*)alloc(256);
  double* partial = (double*)alloc(2048*8);
  char*   w1q     = alloc(nW);
  char*   shared  = alloc(nW);                  // h16 (Mc x 8192 u16 = 16MB) aliases w2q (16MB)
  char*   a8c     = alloc((size_t)Mc*2048);
  ushort* h16     = (ushort*)shared;

  // hq holds one M-segment of int8 h: pick largest segment that fits
  int hqM = 0;
  for (int m = 4096; m >= 1024; m >>= 1)
    if (off + (size_t)m*8192 <= ws_size){ hqM = m; break; }
  if (!hqM) return;
  char* hq = alloc((size_t)hqM*8192);

  absmean2<<<2048,256,0,stream>>>(w1, w2, (int)(nW/4), partial);
  finalize_scales<<<1,256,0,stream>>>(partial, scalebuf, 1.0/(double)nW);
  wquant8<<<(int)(nW/16/256),256,0,stream>>>(w1, w1q, scalebuf, 0);

  for (int s = 0; s < MTOK/hqM; ++s){
    for (int c = 0; c < hqM/Mc; ++c){
      int ch = s*hqM + c*Mc;
      aquant8c<<<Mc,256,0,stream>>>(x + (size_t)ch*2048, a8c, s_a + ch, rowMax + ch);
      gemmK<0,16><<<dim3(64, Mc/256),512,0,stream>>>(
          a8c, w1q, h16, 0, rowMax + ch, nullptr, scalebuf);
      hquant<<<dim3(4, Mc),256,0,stream>>>(h16, hq + (size_t)c*Mc*8192, rowMax + ch);
    }
    // h16 region now dead for this segment -> quantize w2 into it
    wquant8<<<(int)(nW/16/256),256,0,stream>>>(w2, shared, scalebuf, 1);
    gemmK<1,64><<<dim3(16, hqM/256),512,0,stream>>>(
        hq, shared, out, s*hqM, rowMax, s_a, scalebuf);
  }
}